// Round 9
// baseline (870.973 us; speedup 1.0000x reference)
//
#include <hip/hip_runtime.h>

#define B_SZ 4
#define L_SEQ 2048
#define D_MODEL 1024
#define D_INNER 2048
#define D_STATE 16
#define DT_RANK 64
#define NROW (B_SZ * L_SEQ)   // 8192
#define NCHUNK 64
#define CHUNK (L_SEQ / NCHUNK)  // 32
#define KSPLIT 8
#define KCH (D_INNER / KSPLIT)  // 256

typedef __bf16 bf16x8 __attribute__((ext_vector_type(8)));
typedef float  f32x4  __attribute__((ext_vector_type(4)));

__device__ __forceinline__ ushort f2bf(float f) {
    union { float f; uint32_t u; } v; v.f = f;
    const uint32_t r = (v.u + 0x7FFFu + ((v.u >> 16) & 1u)) >> 16;  // RNE
    return (ushort)r;
}
__device__ __forceinline__ float bf2f(ushort u) {
    union { uint32_t u; float f; } v; v.u = ((uint32_t)u) << 16;
    return v.f;
}

// ---------------------------------------------------------------------------
// fp32 -> bf16 flat convert (4 elems/thread)
// ---------------------------------------------------------------------------
__global__ __launch_bounds__(256) void convert_bf16_flat(
    const float* __restrict__ in, ushort* __restrict__ out, int n4)
{
    const int i = blockIdx.x * 256 + threadIdx.x;
    if (i >= n4) return;
    const float4 v = reinterpret_cast<const float4*>(in)[i];
    ushort4 o; o.x = f2bf(v.x); o.y = f2bf(v.y); o.z = f2bf(v.z); o.w = f2bf(v.w);
    reinterpret_cast<ushort4*>(out)[i] = o;
}

// ---------------------------------------------------------------------------
// W[K,N] fp32 -> Wt[N,K] bf16 (32x32 LDS tile transpose)
// ---------------------------------------------------------------------------
__global__ __launch_bounds__(256) void transpose_bf16(
    const float* __restrict__ W, ushort* __restrict__ Wt, int K, int N)
{
    __shared__ float tile[32][33];
    const int n0 = blockIdx.x * 32, k0 = blockIdx.y * 32;
    const int c = threadIdx.x & 31, r = threadIdx.x >> 5;
    #pragma unroll
    for (int p = 0; p < 4; ++p)
        tile[r + p * 8][c] = W[(size_t)(k0 + r + p * 8) * N + n0 + c];
    __syncthreads();
    #pragma unroll
    for (int p = 0; p < 4; ++p)
        Wt[(size_t)(n0 + r + p * 8) * K + k0 + c] = f2bf(tile[c][r + p * 8]);
}

// ---------------------------------------------------------------------------
// bf16 NT GEMM: C[M,N] = A[M,K] * Bt[N,K]^T
// 128x128 tile, BK=64.  Reg-staged (global->reg->LDS) with both-sides XOR
// swizzle (write slot = chunk^(row&7), read slot = chunk^(row&7)) -> 0 bank
// conflicts, and register PREFETCH: tile t+1's global loads issue after the
// post-write barrier, before tile t's MFMAs (latency hides under compute).
// Bijective XCD swizzle on the flattened block id (grid % 8 == 0).
// EPI=0: plain fp32 C.  EPI=1: in_proj epilogue (x fp32 | silu(z) bf16).
// ---------------------------------------------------------------------------
template <int EPI>
__global__ __launch_bounds__(256) void gemm_bf16_nt(
    const ushort* __restrict__ A, const ushort* __restrict__ Bt,
    float* __restrict__ C, ushort* __restrict__ Cz, int M, int N, int K, int ldc)
{
    __shared__ ushort Alds[128][64];
    __shared__ ushort Blds[128][64];
    const int tid  = threadIdx.x;
    const int lane = tid & 63;
    const int wid  = tid >> 6;
    const int wr = wid >> 1, wc = wid & 1;

    // XCD-aware bijective block swizzle (nwg divisible by 8)
    const int gx = gridDim.x;
    int bid = blockIdx.y * gx + blockIdx.x;
    const int cpx = (gx * gridDim.y) >> 3;
    bid = (bid & 7) * cpx + (bid >> 3);
    const int m0 = (bid / gx) * 128, n0 = (bid % gx) * 128;

    const int l15 = lane & 15, l16 = lane >> 4;
    const int swz = l15 & 7;                 // read-side XOR key (= row&7)

    f32x4 acc[4][4] = {};

    // staging: thread tid covers rows (tid>>3)+32i, global chunk tid&7
    const int strow  = tid >> 3;
    const int stchunk = tid & 7;
    const int wslot  = (stchunk ^ (strow & 7)) * 8;   // swizzled LDS slot

    const ushort* gA = A  + (size_t)(m0 + strow) * K + stchunk * 8;
    const ushort* gB = Bt + (size_t)(n0 + strow) * K + stchunk * 8;

    uint4 ra[4], rb[4];
    #pragma unroll
    for (int i = 0; i < 4; ++i) {
        ra[i] = *reinterpret_cast<const uint4*>(gA + (size_t)i * 32 * K);
        rb[i] = *reinterpret_cast<const uint4*>(gB + (size_t)i * 32 * K);
    }

    for (int k0 = 0; k0 < K; k0 += 64) {
        #pragma unroll
        for (int i = 0; i < 4; ++i) {
            *reinterpret_cast<uint4*>(&Alds[strow + i * 32][wslot]) = ra[i];
            *reinterpret_cast<uint4*>(&Blds[strow + i * 32][wslot]) = rb[i];
        }
        __syncthreads();
        if (k0 + 64 < K) {      // prefetch next tile; vmcnt waits at next ds_write
            #pragma unroll
            for (int i = 0; i < 4; ++i) {
                ra[i] = *reinterpret_cast<const uint4*>(gA + (k0 + 64) + (size_t)i * 32 * K);
                rb[i] = *reinterpret_cast<const uint4*>(gB + (k0 + 64) + (size_t)i * 32 * K);
            }
        }
        #pragma unroll
        for (int ks = 0; ks < 64; ks += 32) {
            const int ccb = ks >> 3;         // base chunk: 0 or 4
            bf16x8 af[4], bfr[4];
            #pragma unroll
            for (int mi = 0; mi < 4; ++mi)
                af[mi] = *reinterpret_cast<const bf16x8*>(
                    &Alds[wr * 64 + mi * 16 + l15][((ccb + l16) ^ swz) << 3]);
            #pragma unroll
            for (int ni = 0; ni < 4; ++ni)
                bfr[ni] = *reinterpret_cast<const bf16x8*>(
                    &Blds[wc * 64 + ni * 16 + l15][((ccb + l16) ^ swz) << 3]);
            #pragma unroll
            for (int mi = 0; mi < 4; ++mi)
                #pragma unroll
                for (int ni = 0; ni < 4; ++ni)
                    acc[mi][ni] = __builtin_amdgcn_mfma_f32_16x16x32_bf16(af[mi], bfr[ni], acc[mi][ni], 0, 0, 0);
        }
        __syncthreads();
    }

    #pragma unroll
    for (int mi = 0; mi < 4; ++mi) {
        const int mrow = m0 + wr * 64 + mi * 16 + l16 * 4;
        #pragma unroll
        for (int ni = 0; ni < 4; ++ni) {
            const int ncol = n0 + wc * 64 + ni * 16 + l15;
            #pragma unroll
            for (int r = 0; r < 4; ++r) {
                const float v = acc[mi][ni][r];
                if (EPI == 0) {
                    C[(size_t)(mrow + r) * ldc + ncol] = v;
                } else {
                    if (n0 < 2048) {
                        C[(size_t)(mrow + r) * 2048 + ncol] = v;       // x (fp32)
                    } else {
                        const float s = v / (1.f + __expf(-v));        // silu(z)
                        Cz[(size_t)(mrow + r) * 2048 + (ncol - 2048)] = f2bf(s);
                    }
                }
            }
        }
    }
}

// ---------------------------------------------------------------------------
// K3a: x_proj split-K partial GEMM (N=96, fp32).
// ---------------------------------------------------------------------------
__global__ __launch_bounds__(256) void xproj_partial(
    const float* __restrict__ A, const float* __restrict__ W,
    float* __restrict__ part)
{
    const int m0 = blockIdx.x * 64;
    const int k0 = blockIdx.y * KCH;
    const int tid = threadIdx.x;
    const int tx = tid & 15;
    const int ty = tid >> 4;

    __shared__ float As[16][68];
    __shared__ float Ws[16][96];

    float c[4][6] = {};

    for (int kt = 0; kt < KCH; kt += 16) {
        {
            const int ka = tid & 15, ma = tid >> 4;
            #pragma unroll
            for (int p = 0; p < 4; ++p)
                As[ka][ma + p * 16] = A[(size_t)(m0 + ma + p * 16) * D_INNER + k0 + kt + ka];
        }
        {
            const int kr = tid >> 4;
            const int nc = (tid & 15) * 6;
            #pragma unroll
            for (int j = 0; j < 6; ++j)
                Ws[kr][nc + j] = W[(size_t)(k0 + kt + kr) * 96 + nc + j];
        }
        __syncthreads();
        #pragma unroll
        for (int kk = 0; kk < 16; ++kk) {
            const float4 av = *reinterpret_cast<const float4*>(&As[kk][ty * 4]);
            const float a[4] = {av.x, av.y, av.z, av.w};
            float w[6];
            #pragma unroll
            for (int j = 0; j < 6; ++j) w[j] = Ws[kk][tx * 6 + j];
            #pragma unroll
            for (int i = 0; i < 4; ++i)
                #pragma unroll
                for (int j = 0; j < 6; ++j)
                    c[i][j] = fmaf(a[i], w[j], c[i][j]);
        }
        __syncthreads();
    }

    #pragma unroll
    for (int i = 0; i < 4; ++i) {
        const int m = m0 + ty * 4 + i;
        #pragma unroll
        for (int j = 0; j < 6; ++j)
            part[((size_t)blockIdx.y * NROW + m) * 96 + tx * 6 + j] = c[i][j];
    }
}

__global__ __launch_bounds__(256) void xproj_reduce(
    const float* __restrict__ part, float* __restrict__ x_dbl)
{
    const int i = blockIdx.x * 256 + threadIdx.x;
    if (i >= NROW * 96 / 4) return;
    const float4* p4 = reinterpret_cast<const float4*>(part);
    const size_t stride = (size_t)NROW * 96 / 4;
    float4 s = p4[i];
    #pragma unroll
    for (int ks = 1; ks < KSPLIT; ++ks) {
        const float4 v = p4[(size_t)ks * stride + i];
        s.x += v.x; s.y += v.y; s.z += v.z; s.w += v.w;
    }
    reinterpret_cast<float4*>(x_dbl)[i] = s;
}

// ---------------------------------------------------------------------------
// Depthwise conv (taps x[t-6..t-3]) + bias + SiLU, float4-vectorized:
// one thread = 4 channels of one (b,t).
// ---------------------------------------------------------------------------
__global__ __launch_bounds__(256) void conv_silu_kernel(
    const float* __restrict__ x, const float* __restrict__ conv_w,
    const float* __restrict__ conv_b, float* __restrict__ x_bld)
{
    const int idx = blockIdx.x * 256 + threadIdx.x;
    if (idx >= B_SZ * L_SEQ * D_INNER / 4) return;
    const int d4 = (idx & 511) * 4;
    const int t  = (idx >> 9) & (L_SEQ - 1);
    const int b  = idx >> 20;

    float wk[4][4];
    #pragma unroll
    for (int j = 0; j < 4; ++j) {
        const float4 w = *reinterpret_cast<const float4*>(&conv_w[(d4 + j) * 4]);
        wk[j][0] = w.x; wk[j][1] = w.y; wk[j][2] = w.z; wk[j][3] = w.w;
    }
    const float4 cb = *reinterpret_cast<const float4*>(&conv_b[d4]);
    float acc[4] = {cb.x, cb.y, cb.z, cb.w};

    const size_t chbase = (size_t)b * L_SEQ * D_INNER + d4;
    #pragma unroll
    for (int k = 0; k < 4; ++k) {
        const int tt = t - 6 + k;
        if (tt >= 0) {
            const float4 xv = *reinterpret_cast<const float4*>(&x[chbase + (size_t)tt * D_INNER]);
            acc[0] = fmaf(wk[0][k], xv.x, acc[0]);
            acc[1] = fmaf(wk[1][k], xv.y, acc[1]);
            acc[2] = fmaf(wk[2][k], xv.z, acc[2]);
            acc[3] = fmaf(wk[3][k], xv.w, acc[3]);
        }
    }
    float4 o;
    o.x = acc[0] / (1.f + __expf(-acc[0]));
    o.y = acc[1] / (1.f + __expf(-acc[1]));
    o.z = acc[2] / (1.f + __expf(-acc[2]));
    o.w = acc[3] / (1.f + __expf(-acc[3]));
    *reinterpret_cast<float4*>(&x_bld[chbase + (size_t)t * D_INNER]) = o;
}

// ---------------------------------------------------------------------------
// delta = softplus(dt_low @ dt_proj_w + 2*bias) -> delta[M][2048]
// ---------------------------------------------------------------------------
__global__ __launch_bounds__(256) void dt_softplus_kernel(
    const float* __restrict__ x_dbl, const float* __restrict__ W,
    const float* __restrict__ bias, float* __restrict__ delta)
{
    __shared__ float a[16][64];
    const int tid = threadIdx.x;
    const int m0 = blockIdx.y * 16;
    const int d = blockIdx.x * 256 + tid;

    {
        const int r = tid & 63, i = tid >> 6;
        #pragma unroll
        for (int p = 0; p < 4; ++p)
            a[i + p * 4][r] = x_dbl[(size_t)(m0 + i + p * 4) * 96 + r];
    }
    __syncthreads();

    float acc[16] = {};
    for (int r = 0; r < 64; ++r) {
        const float w = W[(size_t)r * D_INNER + d];
        #pragma unroll
        for (int mi = 0; mi < 16; ++mi) acc[mi] = fmaf(a[mi][r], w, acc[mi]);
    }
    const float b2 = 2.0f * bias[d];
    #pragma unroll
    for (int mi = 0; mi < 16; ++mi) {
        const float v = acc[mi] + b2;
        const float sp = (v > 20.0f) ? v : log1pf(__expf(v));
        delta[(size_t)(m0 + mi) * D_INNER + d] = sp;
    }
}

// ---------------------------------------------------------------------------
// Chunked parallel scan, thread-local 16-state (see round 4/5 notes).
// ---------------------------------------------------------------------------
__global__ __launch_bounds__(256) void scan_pass1(
    const float* __restrict__ delta, const float* __restrict__ u_,
    const float* __restrict__ x_dbl, const float* __restrict__ A_log,
    float* __restrict__ hfin, float* __restrict__ Ssum)
{
    const int g = blockIdx.x * 256 + threadIdx.x;  // 0 .. 524287
    const int d = g & (D_INNER - 1);
    const int b = (g >> 11) & 3;
    const int c = g >> 13;

    float A[D_STATE];
    #pragma unroll
    for (int q = 0; q < 4; ++q) {
        const float4 al = *reinterpret_cast<const float4*>(&A_log[d * D_STATE + q * 4]);
        A[q * 4 + 0] = -__expf(al.x); A[q * 4 + 1] = -__expf(al.y);
        A[q * 4 + 2] = -__expf(al.z); A[q * 4 + 3] = -__expf(al.w);
    }

    const int t0 = c * CHUNK;
    const size_t base2048 = (size_t)b * L_SEQ * D_INNER + d;
    const size_t base96   = (size_t)b * L_SEQ * 96;

    float h[D_STATE] = {};
    float S = 0.f;
    for (int i = 0; i < CHUNK; ++i) {
        const int t = t0 + i;
        const float dv = delta[base2048 + (size_t)t * D_INNER];
        const float uv = u_[base2048 + (size_t)t * D_INNER];
        float Bv[D_STATE];
        #pragma unroll
        for (int q = 0; q < 4; ++q)
            *reinterpret_cast<float4*>(&Bv[q * 4]) =
                *reinterpret_cast<const float4*>(&x_dbl[base96 + (size_t)t * 96 + DT_RANK + q * 4]);
        const float du = dv * uv;
        S += dv;
        #pragma unroll
        for (int n = 0; n < D_STATE; ++n)
            h[n] = fmaf(h[n], __expf(dv * A[n]), du * Bv[n]);
    }
    const size_t sidx = (size_t)(c * B_SZ + b) * D_INNER + d;
    #pragma unroll
    for (int q = 0; q < 4; ++q)
        *reinterpret_cast<float4*>(&hfin[sidx * D_STATE + q * 4]) =
            *reinterpret_cast<const float4*>(&h[q * 4]);
    Ssum[sidx] = S;
}

__global__ __launch_bounds__(256) void scan_pass2(
    float* __restrict__ hfin, const float* __restrict__ Ssum,
    const float* __restrict__ A_log)
{
    const int g = blockIdx.x * 256 + threadIdx.x;  // 0 .. 131071
    const int n = g & 15;
    const int d = (g >> 4) & (D_INNER - 1);
    const int b = g >> 15;
    const float A = -__expf(A_log[d * D_STATE + n]);

    float H = 0.f;
    #pragma unroll 4
    for (int c = 0; c < NCHUNK; ++c) {
        const size_t sidx = (size_t)(c * B_SZ + b) * D_INNER + d;
        const float P = __expf(A * Ssum[sidx]);
        const float hc = hfin[sidx * D_STATE + n];
        hfin[sidx * D_STATE + n] = H;       // Hinit in place
        H = fmaf(H, P, hc);
    }
}

__global__ __launch_bounds__(256) void scan_pass3(
    const float* __restrict__ delta, const float* __restrict__ u_,
    const ushort* __restrict__ z_silu, const float* __restrict__ x_dbl,
    const float* __restrict__ A_log, const float* __restrict__ D_skip,
    const float* __restrict__ Hinit, ushort* __restrict__ y_bf)
{
    const int g = blockIdx.x * 256 + threadIdx.x;  // 0 .. 524287
    const int d = g & (D_INNER - 1);
    const int b = (g >> 11) & 3;
    const int c = g >> 13;

    float A[D_STATE];
    #pragma unroll
    for (int q = 0; q < 4; ++q) {
        const float4 al = *reinterpret_cast<const float4*>(&A_log[d * D_STATE + q * 4]);
        A[q * 4 + 0] = -__expf(al.x); A[q * 4 + 1] = -__expf(al.y);
        A[q * 4 + 2] = -__expf(al.z); A[q * 4 + 3] = -__expf(al.w);
    }
    const float Dd = D_skip[d];

    const int t0 = c * CHUNK;
    const size_t base2048 = (size_t)b * L_SEQ * D_INNER + d;
    const size_t base96   = (size_t)b * L_SEQ * 96;

    float h[D_STATE];
    const size_t sidx = (size_t)(c * B_SZ + b) * D_INNER + d;
    #pragma unroll
    for (int q = 0; q < 4; ++q)
        *reinterpret_cast<float4*>(&h[q * 4]) =
            *reinterpret_cast<const float4*>(&Hinit[sidx * D_STATE + q * 4]);

    for (int i = 0; i < CHUNK; ++i) {
        const int t = t0 + i;
        const size_t off = base2048 + (size_t)t * D_INNER;
        const float dv = delta[off];
        const float uv = u_[off];
        const float zs = bf2f(z_silu[off]);
        float Bv[D_STATE], Cv[D_STATE];
        #pragma unroll
        for (int q = 0; q < 4; ++q) {
            *reinterpret_cast<float4*>(&Bv[q * 4]) =
                *reinterpret_cast<const float4*>(&x_dbl[base96 + (size_t)t * 96 + DT_RANK + q * 4]);
            *reinterpret_cast<float4*>(&Cv[q * 4]) =
                *reinterpret_cast<const float4*>(&x_dbl[base96 + (size_t)t * 96 + DT_RANK + D_STATE + q * 4]);
        }
        const float du = dv * uv;
        float y = 0.f;
        #pragma unroll
        for (int n = 0; n < D_STATE; ++n) {
            h[n] = fmaf(h[n], __expf(dv * A[n]), du * Bv[n]);
            y = fmaf(h[n], Cv[n], y);
        }
        const float yv = (y + uv * Dd) * zs;
        y_bf[off] = f2bf(yv);
    }
}

// ---------------------------------------------------------------------------
extern "C" void kernel_launch(void* const* d_in, const int* in_sizes, int n_in,
                              void* d_out, int out_size, void* d_ws, size_t ws_size,
                              hipStream_t stream)
{
    const float* hs         = (const float*)d_in[0];
    const float* in_proj_w  = (const float*)d_in[1];
    const float* conv_w     = (const float*)d_in[2];
    const float* conv_b     = (const float*)d_in[3];
    const float* x_proj_w   = (const float*)d_in[4];
    const float* dt_proj_w  = (const float*)d_in[5];
    const float* dt_proj_b  = (const float*)d_in[6];
    const float* A_log      = (const float*)d_in[7];
    const float* D_skip     = (const float*)d_in[8];
    const float* out_proj_w = (const float*)d_in[9];
    float* out = (float*)d_out;

    // Workspace (f32 elems), total 244.3 MB (known-good size):
    //   regA   67.1 MB  x_f32 [8192][2048] -> (dead after conv) delta
    //   x_bld  67.1 MB
    //   x_dbl   3.1 MB
    //   R1     35.7 MB  phase A: hs_bf+Wt1 | phase B: part | phase C: hfin+Ssum
    //   y_bf   33.5 MB
    //   z_silu 33.5 MB
    //   Wt6     4.2 MB
    float* ws    = (float*)d_ws;
    float* regA  = ws;
    float* x_bld = regA + (size_t)NROW * 2048;
    float* x_dbl = x_bld + (size_t)NROW * 2048;
    float* R1    = x_dbl + (size_t)NROW * 96;
    float* ybff  = R1 + 8912896;
    float* zbff  = ybff + 8388608;
    float* wt6f  = zbff + 8388608;

    ushort* hs_bf  = (ushort*)R1;
    ushort* Wt1    = (ushort*)(R1 + 4194304);
    float*  part   = R1;
    float*  hfin   = R1;
    float*  Ssum   = R1 + 8388608;
    ushort* y_bf   = (ushort*)ybff;
    ushort* z_silu = (ushort*)zbff;
    ushort* Wt6    = (ushort*)wt6f;

    // C0: converts (hs flat; weights transposed to [N,K] bf16)
    hipLaunchKernelGGL(convert_bf16_flat, dim3(8192), dim3(256), 0, stream,
                       hs, hs_bf, NROW * D_MODEL / 4);
    hipLaunchKernelGGL(transpose_bf16, dim3(4096 / 32, 1024 / 32), dim3(256), 0, stream,
                       in_proj_w, Wt1, 1024, 4096);
    hipLaunchKernelGGL(transpose_bf16, dim3(1024 / 32, 2048 / 32), dim3(256), 0, stream,
                       out_proj_w, Wt6, 2048, 1024);

    // K1: in_proj (bf16 MFMA NT, reg-staged+swz+prefetch) -> x fp32 + silu(z) bf16
    hipLaunchKernelGGL((gemm_bf16_nt<1>), dim3(4096 / 128, NROW / 128), dim3(256), 0, stream,
                       hs_bf, Wt1, regA, z_silu, NROW, 4096, D_MODEL, 0);

    // K2: depthwise conv + bias + silu -> x_bld (float4-vectorized)
    {
        const int total4 = B_SZ * L_SEQ * D_INNER / 4;
        hipLaunchKernelGGL(conv_silu_kernel, dim3((total4 + 255) / 256), dim3(256), 0, stream,
                           regA, conv_w, conv_b, x_bld);
    }
    // K3: x_dbl = x_bld @ x_proj_w  (split-K fp32)
    {
        hipLaunchKernelGGL(xproj_partial, dim3(NROW / 64, KSPLIT), dim3(256), 0, stream,
                           x_bld, x_proj_w, part);
        hipLaunchKernelGGL(xproj_reduce, dim3(NROW * 96 / 4 / 256), dim3(256), 0, stream,
                           part, x_dbl);
    }
    // K4: delta -> regA (x dead after conv)
    {
        dim3 grid(D_INNER / 256, NROW / 16);
        hipLaunchKernelGGL(dt_softplus_kernel, grid, dim3(256), 0, stream,
                           x_dbl, dt_proj_w, dt_proj_b, regA);
    }
    // K5: chunked scan (thread-local 16-state); pass3 emits bf16 y directly
    {
        const int total1 = B_SZ * D_INNER * NCHUNK;          // 524,288
        hipLaunchKernelGGL(scan_pass1, dim3(total1 / 256), dim3(256), 0, stream,
                           regA, x_bld, x_dbl, A_log, hfin, Ssum);
        const int total2 = B_SZ * D_INNER * D_STATE;         // 131,072
        hipLaunchKernelGGL(scan_pass2, dim3(total2 / 256), dim3(256), 0, stream,
                           hfin, Ssum, A_log);
        hipLaunchKernelGGL(scan_pass3, dim3(total1 / 256), dim3(256), 0, stream,
                           regA, x_bld, z_silu, x_dbl, A_log, D_skip, hfin, y_bf);
    }
    // K6: out = y @ out_proj_w  (bf16 MFMA NT, reg-staged+swz+prefetch)
    hipLaunchKernelGGL((gemm_bf16_nt<0>), dim3(1024 / 128, NROW / 128), dim3(256), 0, stream,
                       y_bf, Wt6, out, (ushort*)nullptr, NROW, 1024, D_INNER, 1024);
}

// Round 10
// 857.227 us; speedup vs baseline: 1.0160x; 1.0160x over previous
//
#include <hip/hip_runtime.h>

#define B_SZ 4
#define L_SEQ 2048
#define D_MODEL 1024
#define D_INNER 2048
#define D_STATE 16
#define DT_RANK 64
#define NROW (B_SZ * L_SEQ)   // 8192
#define NCHUNK 64
#define CHUNK (L_SEQ / NCHUNK)  // 32
#define KSPLIT 8
#define KCH (D_INNER / KSPLIT)  // 256

typedef __bf16 bf16x8 __attribute__((ext_vector_type(8)));
typedef float  f32x4  __attribute__((ext_vector_type(4)));

__device__ __forceinline__ ushort f2bf(float f) {
    union { float f; uint32_t u; } v; v.f = f;
    const uint32_t r = (v.u + 0x7FFFu + ((v.u >> 16) & 1u)) >> 16;  // RNE
    return (ushort)r;
}
__device__ __forceinline__ float bf2f(ushort u) {
    union { uint32_t u; float f; } v; v.u = ((uint32_t)u) << 16;
    return v.f;
}

// ---------------------------------------------------------------------------
// fp32 -> bf16 flat convert (4 elems/thread)
// ---------------------------------------------------------------------------
__global__ __launch_bounds__(256) void convert_bf16_flat(
    const float* __restrict__ in, ushort* __restrict__ out, int n4)
{
    const int i = blockIdx.x * 256 + threadIdx.x;
    if (i >= n4) return;
    const float4 v = reinterpret_cast<const float4*>(in)[i];
    ushort4 o; o.x = f2bf(v.x); o.y = f2bf(v.y); o.z = f2bf(v.z); o.w = f2bf(v.w);
    reinterpret_cast<ushort4*>(out)[i] = o;
}

// ---------------------------------------------------------------------------
// W[K,N] fp32 -> Wt[N,K] bf16 (32x32 LDS tile transpose)
// ---------------------------------------------------------------------------
__global__ __launch_bounds__(256) void transpose_bf16(
    const float* __restrict__ W, ushort* __restrict__ Wt, int K, int N)
{
    __shared__ float tile[32][33];
    const int n0 = blockIdx.x * 32, k0 = blockIdx.y * 32;
    const int c = threadIdx.x & 31, r = threadIdx.x >> 5;
    #pragma unroll
    for (int p = 0; p < 4; ++p)
        tile[r + p * 8][c] = W[(size_t)(k0 + r + p * 8) * N + n0 + c];
    __syncthreads();
    #pragma unroll
    for (int p = 0; p < 4; ++p)
        Wt[(size_t)(n0 + r + p * 8) * K + k0 + c] = f2bf(tile[c][r + p * 8]);
}

// ---------------------------------------------------------------------------
// bf16 NT GEMM: C[M,N] = A[M,K] * Bt[N,K]^T
// 128x128 tile, BK=64.  Reg-staged (global->reg->LDS) with both-sides XOR
// swizzle (slot = chunk^(row&7) on write AND read) -> 0 bank conflicts, and
// register PREFETCH of tile t+1 between the post-write barrier and tile t's
// MFMAs.  Plain row-major block mapping (XCD swizzle REVERTED: round 9
// showed it thrashes L2 at this L2/L3-resident problem size: FETCH 82->395MB).
// EPI=0: plain fp32 C.  EPI=1: in_proj epilogue (x fp32 | silu(z) bf16).
// ---------------------------------------------------------------------------
template <int EPI>
__global__ __launch_bounds__(256) void gemm_bf16_nt(
    const ushort* __restrict__ A, const ushort* __restrict__ Bt,
    float* __restrict__ C, ushort* __restrict__ Cz, int M, int N, int K, int ldc)
{
    __shared__ ushort Alds[128][64];
    __shared__ ushort Blds[128][64];
    const int tid  = threadIdx.x;
    const int lane = tid & 63;
    const int wid  = tid >> 6;
    const int wr = wid >> 1, wc = wid & 1;
    const int m0 = blockIdx.y * 128, n0 = blockIdx.x * 128;
    const int l15 = lane & 15, l16 = lane >> 4;
    const int swz = l15 & 7;                 // read-side XOR key (= row&7)

    f32x4 acc[4][4] = {};

    // staging: thread tid covers rows (tid>>3)+32i, global chunk tid&7
    const int strow  = tid >> 3;
    const int stchunk = tid & 7;
    const int wslot  = (stchunk ^ (strow & 7)) * 8;   // swizzled LDS slot

    const ushort* gA = A  + (size_t)(m0 + strow) * K + stchunk * 8;
    const ushort* gB = Bt + (size_t)(n0 + strow) * K + stchunk * 8;

    uint4 ra[4], rb[4];
    #pragma unroll
    for (int i = 0; i < 4; ++i) {
        ra[i] = *reinterpret_cast<const uint4*>(gA + (size_t)i * 32 * K);
        rb[i] = *reinterpret_cast<const uint4*>(gB + (size_t)i * 32 * K);
    }

    for (int k0 = 0; k0 < K; k0 += 64) {
        #pragma unroll
        for (int i = 0; i < 4; ++i) {
            *reinterpret_cast<uint4*>(&Alds[strow + i * 32][wslot]) = ra[i];
            *reinterpret_cast<uint4*>(&Blds[strow + i * 32][wslot]) = rb[i];
        }
        __syncthreads();
        if (k0 + 64 < K) {      // prefetch next tile; hides under MFMAs
            #pragma unroll
            for (int i = 0; i < 4; ++i) {
                ra[i] = *reinterpret_cast<const uint4*>(gA + (k0 + 64) + (size_t)i * 32 * K);
                rb[i] = *reinterpret_cast<const uint4*>(gB + (k0 + 64) + (size_t)i * 32 * K);
            }
        }
        #pragma unroll
        for (int ks = 0; ks < 64; ks += 32) {
            const int ccb = ks >> 3;         // base chunk: 0 or 4
            bf16x8 af[4], bfr[4];
            #pragma unroll
            for (int mi = 0; mi < 4; ++mi)
                af[mi] = *reinterpret_cast<const bf16x8*>(
                    &Alds[wr * 64 + mi * 16 + l15][((ccb + l16) ^ swz) << 3]);
            #pragma unroll
            for (int ni = 0; ni < 4; ++ni)
                bfr[ni] = *reinterpret_cast<const bf16x8*>(
                    &Blds[wc * 64 + ni * 16 + l15][((ccb + l16) ^ swz) << 3]);
            #pragma unroll
            for (int mi = 0; mi < 4; ++mi)
                #pragma unroll
                for (int ni = 0; ni < 4; ++ni)
                    acc[mi][ni] = __builtin_amdgcn_mfma_f32_16x16x32_bf16(af[mi], bfr[ni], acc[mi][ni], 0, 0, 0);
        }
        __syncthreads();
    }

    #pragma unroll
    for (int mi = 0; mi < 4; ++mi) {
        const int mrow = m0 + wr * 64 + mi * 16 + l16 * 4;
        #pragma unroll
        for (int ni = 0; ni < 4; ++ni) {
            const int ncol = n0 + wc * 64 + ni * 16 + l15;
            #pragma unroll
            for (int r = 0; r < 4; ++r) {
                const float v = acc[mi][ni][r];
                if (EPI == 0) {
                    C[(size_t)(mrow + r) * ldc + ncol] = v;
                } else {
                    if (n0 < 2048) {
                        C[(size_t)(mrow + r) * 2048 + ncol] = v;       // x (fp32)
                    } else {
                        const float s = v / (1.f + __expf(-v));        // silu(z)
                        Cz[(size_t)(mrow + r) * 2048 + (ncol - 2048)] = f2bf(s);
                    }
                }
            }
        }
    }
}

// ---------------------------------------------------------------------------
// K3a: x_proj split-K partial GEMM (N=96, fp32).
// ---------------------------------------------------------------------------
__global__ __launch_bounds__(256) void xproj_partial(
    const float* __restrict__ A, const float* __restrict__ W,
    float* __restrict__ part)
{
    const int m0 = blockIdx.x * 64;
    const int k0 = blockIdx.y * KCH;
    const int tid = threadIdx.x;
    const int tx = tid & 15;
    const int ty = tid >> 4;

    __shared__ float As[16][68];
    __shared__ float Ws[16][96];

    float c[4][6] = {};

    for (int kt = 0; kt < KCH; kt += 16) {
        {
            const int ka = tid & 15, ma = tid >> 4;
            #pragma unroll
            for (int p = 0; p < 4; ++p)
                As[ka][ma + p * 16] = A[(size_t)(m0 + ma + p * 16) * D_INNER + k0 + kt + ka];
        }
        {
            const int kr = tid >> 4;
            const int nc = (tid & 15) * 6;
            #pragma unroll
            for (int j = 0; j < 6; ++j)
                Ws[kr][nc + j] = W[(size_t)(k0 + kt + kr) * 96 + nc + j];
        }
        __syncthreads();
        #pragma unroll
        for (int kk = 0; kk < 16; ++kk) {
            const float4 av = *reinterpret_cast<const float4*>(&As[kk][ty * 4]);
            const float a[4] = {av.x, av.y, av.z, av.w};
            float w[6];
            #pragma unroll
            for (int j = 0; j < 6; ++j) w[j] = Ws[kk][tx * 6 + j];
            #pragma unroll
            for (int i = 0; i < 4; ++i)
                #pragma unroll
                for (int j = 0; j < 6; ++j)
                    c[i][j] = fmaf(a[i], w[j], c[i][j]);
        }
        __syncthreads();
    }

    #pragma unroll
    for (int i = 0; i < 4; ++i) {
        const int m = m0 + ty * 4 + i;
        #pragma unroll
        for (int j = 0; j < 6; ++j)
            part[((size_t)blockIdx.y * NROW + m) * 96 + tx * 6 + j] = c[i][j];
    }
}

__global__ __launch_bounds__(256) void xproj_reduce(
    const float* __restrict__ part, float* __restrict__ x_dbl)
{
    const int i = blockIdx.x * 256 + threadIdx.x;
    if (i >= NROW * 96 / 4) return;
    const float4* p4 = reinterpret_cast<const float4*>(part);
    const size_t stride = (size_t)NROW * 96 / 4;
    float4 s = p4[i];
    #pragma unroll
    for (int ks = 1; ks < KSPLIT; ++ks) {
        const float4 v = p4[(size_t)ks * stride + i];
        s.x += v.x; s.y += v.y; s.z += v.z; s.w += v.w;
    }
    reinterpret_cast<float4*>(x_dbl)[i] = s;
}

// ---------------------------------------------------------------------------
// Depthwise conv (taps x[t-6..t-3]) + bias + SiLU, float4-vectorized.
// ---------------------------------------------------------------------------
__global__ __launch_bounds__(256) void conv_silu_kernel(
    const float* __restrict__ x, const float* __restrict__ conv_w,
    const float* __restrict__ conv_b, float* __restrict__ x_bld)
{
    const int idx = blockIdx.x * 256 + threadIdx.x;
    if (idx >= B_SZ * L_SEQ * D_INNER / 4) return;
    const int d4 = (idx & 511) * 4;
    const int t  = (idx >> 9) & (L_SEQ - 1);
    const int b  = idx >> 20;

    float wk[4][4];
    #pragma unroll
    for (int j = 0; j < 4; ++j) {
        const float4 w = *reinterpret_cast<const float4*>(&conv_w[(d4 + j) * 4]);
        wk[j][0] = w.x; wk[j][1] = w.y; wk[j][2] = w.z; wk[j][3] = w.w;
    }
    const float4 cb = *reinterpret_cast<const float4*>(&conv_b[d4]);
    float acc[4] = {cb.x, cb.y, cb.z, cb.w};

    const size_t chbase = (size_t)b * L_SEQ * D_INNER + d4;
    #pragma unroll
    for (int k = 0; k < 4; ++k) {
        const int tt = t - 6 + k;
        if (tt >= 0) {
            const float4 xv = *reinterpret_cast<const float4*>(&x[chbase + (size_t)tt * D_INNER]);
            acc[0] = fmaf(wk[0][k], xv.x, acc[0]);
            acc[1] = fmaf(wk[1][k], xv.y, acc[1]);
            acc[2] = fmaf(wk[2][k], xv.z, acc[2]);
            acc[3] = fmaf(wk[3][k], xv.w, acc[3]);
        }
    }
    float4 o;
    o.x = acc[0] / (1.f + __expf(-acc[0]));
    o.y = acc[1] / (1.f + __expf(-acc[1]));
    o.z = acc[2] / (1.f + __expf(-acc[2]));
    o.w = acc[3] / (1.f + __expf(-acc[3]));
    *reinterpret_cast<float4*>(&x_bld[chbase + (size_t)t * D_INNER]) = o;
}

// ---------------------------------------------------------------------------
// delta = softplus(dt_low @ dt_proj_w + 2*bias) -> delta[M][2048]
// ---------------------------------------------------------------------------
__global__ __launch_bounds__(256) void dt_softplus_kernel(
    const float* __restrict__ x_dbl, const float* __restrict__ W,
    const float* __restrict__ bias, float* __restrict__ delta)
{
    __shared__ float a[16][64];
    const int tid = threadIdx.x;
    const int m0 = blockIdx.y * 16;
    const int d = blockIdx.x * 256 + tid;

    {
        const int r = tid & 63, i = tid >> 6;
        #pragma unroll
        for (int p = 0; p < 4; ++p)
            a[i + p * 4][r] = x_dbl[(size_t)(m0 + i + p * 4) * 96 + r];
    }
    __syncthreads();

    float acc[16] = {};
    for (int r = 0; r < 64; ++r) {
        const float w = W[(size_t)r * D_INNER + d];
        #pragma unroll
        for (int mi = 0; mi < 16; ++mi) acc[mi] = fmaf(a[mi][r], w, acc[mi]);
    }
    const float b2 = 2.0f * bias[d];
    #pragma unroll
    for (int mi = 0; mi < 16; ++mi) {
        const float v = acc[mi] + b2;
        const float sp = (v > 20.0f) ? v : log1pf(__expf(v));
        delta[(size_t)(m0 + mi) * D_INNER + d] = sp;
    }
}

// ---------------------------------------------------------------------------
// Chunked parallel scan, thread-local 16-state (see round 4/5 notes).
// ---------------------------------------------------------------------------
__global__ __launch_bounds__(256) void scan_pass1(
    const float* __restrict__ delta, const float* __restrict__ u_,
    const float* __restrict__ x_dbl, const float* __restrict__ A_log,
    float* __restrict__ hfin, float* __restrict__ Ssum)
{
    const int g = blockIdx.x * 256 + threadIdx.x;  // 0 .. 524287
    const int d = g & (D_INNER - 1);
    const int b = (g >> 11) & 3;
    const int c = g >> 13;

    float A[D_STATE];
    #pragma unroll
    for (int q = 0; q < 4; ++q) {
        const float4 al = *reinterpret_cast<const float4*>(&A_log[d * D_STATE + q * 4]);
        A[q * 4 + 0] = -__expf(al.x); A[q * 4 + 1] = -__expf(al.y);
        A[q * 4 + 2] = -__expf(al.z); A[q * 4 + 3] = -__expf(al.w);
    }

    const int t0 = c * CHUNK;
    const size_t base2048 = (size_t)b * L_SEQ * D_INNER + d;
    const size_t base96   = (size_t)b * L_SEQ * 96;

    float h[D_STATE] = {};
    float S = 0.f;
    for (int i = 0; i < CHUNK; ++i) {
        const int t = t0 + i;
        const float dv = delta[base2048 + (size_t)t * D_INNER];
        const float uv = u_[base2048 + (size_t)t * D_INNER];
        float Bv[D_STATE];
        #pragma unroll
        for (int q = 0; q < 4; ++q)
            *reinterpret_cast<float4*>(&Bv[q * 4]) =
                *reinterpret_cast<const float4*>(&x_dbl[base96 + (size_t)t * 96 + DT_RANK + q * 4]);
        const float du = dv * uv;
        S += dv;
        #pragma unroll
        for (int n = 0; n < D_STATE; ++n)
            h[n] = fmaf(h[n], __expf(dv * A[n]), du * Bv[n]);
    }
    const size_t sidx = (size_t)(c * B_SZ + b) * D_INNER + d;
    #pragma unroll
    for (int q = 0; q < 4; ++q)
        *reinterpret_cast<float4*>(&hfin[sidx * D_STATE + q * 4]) =
            *reinterpret_cast<const float4*>(&h[q * 4]);
    Ssum[sidx] = S;
}

__global__ __launch_bounds__(256) void scan_pass2(
    float* __restrict__ hfin, const float* __restrict__ Ssum,
    const float* __restrict__ A_log)
{
    const int g = blockIdx.x * 256 + threadIdx.x;  // 0 .. 131071
    const int n = g & 15;
    const int d = (g >> 4) & (D_INNER - 1);
    const int b = g >> 15;
    const float A = -__expf(A_log[d * D_STATE + n]);

    float H = 0.f;
    #pragma unroll 4
    for (int c = 0; c < NCHUNK; ++c) {
        const size_t sidx = (size_t)(c * B_SZ + b) * D_INNER + d;
        const float P = __expf(A * Ssum[sidx]);
        const float hc = hfin[sidx * D_STATE + n];
        hfin[sidx * D_STATE + n] = H;       // Hinit in place
        H = fmaf(H, P, hc);
    }
}

__global__ __launch_bounds__(256) void scan_pass3(
    const float* __restrict__ delta, const float* __restrict__ u_,
    const ushort* __restrict__ z_silu, const float* __restrict__ x_dbl,
    const float* __restrict__ A_log, const float* __restrict__ D_skip,
    const float* __restrict__ Hinit, ushort* __restrict__ y_bf)
{
    const int g = blockIdx.x * 256 + threadIdx.x;  // 0 .. 524287
    const int d = g & (D_INNER - 1);
    const int b = (g >> 11) & 3;
    const int c = g >> 13;

    float A[D_STATE];
    #pragma unroll
    for (int q = 0; q < 4; ++q) {
        const float4 al = *reinterpret_cast<const float4*>(&A_log[d * D_STATE + q * 4]);
        A[q * 4 + 0] = -__expf(al.x); A[q * 4 + 1] = -__expf(al.y);
        A[q * 4 + 2] = -__expf(al.z); A[q * 4 + 3] = -__expf(al.w);
    }
    const float Dd = D_skip[d];

    const int t0 = c * CHUNK;
    const size_t base2048 = (size_t)b * L_SEQ * D_INNER + d;
    const size_t base96   = (size_t)b * L_SEQ * 96;

    float h[D_STATE];
    const size_t sidx = (size_t)(c * B_SZ + b) * D_INNER + d;
    #pragma unroll
    for (int q = 0; q < 4; ++q)
        *reinterpret_cast<float4*>(&h[q * 4]) =
            *reinterpret_cast<const float4*>(&Hinit[sidx * D_STATE + q * 4]);

    for (int i = 0; i < CHUNK; ++i) {
        const int t = t0 + i;
        const size_t off = base2048 + (size_t)t * D_INNER;
        const float dv = delta[off];
        const float uv = u_[off];
        const float zs = bf2f(z_silu[off]);
        float Bv[D_STATE], Cv[D_STATE];
        #pragma unroll
        for (int q = 0; q < 4; ++q) {
            *reinterpret_cast<float4*>(&Bv[q * 4]) =
                *reinterpret_cast<const float4*>(&x_dbl[base96 + (size_t)t * 96 + DT_RANK + q * 4]);
            *reinterpret_cast<float4*>(&Cv[q * 4]) =
                *reinterpret_cast<const float4*>(&x_dbl[base96 + (size_t)t * 96 + DT_RANK + D_STATE + q * 4]);
        }
        const float du = dv * uv;
        float y = 0.f;
        #pragma unroll
        for (int n = 0; n < D_STATE; ++n) {
            h[n] = fmaf(h[n], __expf(dv * A[n]), du * Bv[n]);
            y = fmaf(h[n], Cv[n], y);
        }
        const float yv = (y + uv * Dd) * zs;
        y_bf[off] = f2bf(yv);
    }
}

// ---------------------------------------------------------------------------
extern "C" void kernel_launch(void* const* d_in, const int* in_sizes, int n_in,
                              void* d_out, int out_size, void* d_ws, size_t ws_size,
                              hipStream_t stream)
{
    const float* hs         = (const float*)d_in[0];
    const float* in_proj_w  = (const float*)d_in[1];
    const float* conv_w     = (const float*)d_in[2];
    const float* conv_b     = (const float*)d_in[3];
    const float* x_proj_w   = (const float*)d_in[4];
    const float* dt_proj_w  = (const float*)d_in[5];
    const float* dt_proj_b  = (const float*)d_in[6];
    const float* A_log      = (const float*)d_in[7];
    const float* D_skip     = (const float*)d_in[8];
    const float* out_proj_w = (const float*)d_in[9];
    float* out = (float*)d_out;

    // Workspace (f32 elems), total 244.3 MB (known-good size):
    //   regA   67.1 MB  x_f32 [8192][2048] -> (dead after conv) delta
    //   x_bld  67.1 MB
    //   x_dbl   3.1 MB
    //   R1     35.7 MB  phase A: hs_bf+Wt1 | phase B: part | phase C: hfin+Ssum
    //   y_bf   33.5 MB
    //   z_silu 33.5 MB
    //   Wt6     4.2 MB
    float* ws    = (float*)d_ws;
    float* regA  = ws;
    float* x_bld = regA + (size_t)NROW * 2048;
    float* x_dbl = x_bld + (size_t)NROW * 2048;
    float* R1    = x_dbl + (size_t)NROW * 96;
    float* ybff  = R1 + 8912896;
    float* zbff  = ybff + 8388608;
    float* wt6f  = zbff + 8388608;

    ushort* hs_bf  = (ushort*)R1;
    ushort* Wt1    = (ushort*)(R1 + 4194304);
    float*  part   = R1;
    float*  hfin   = R1;
    float*  Ssum   = R1 + 8388608;
    ushort* y_bf   = (ushort*)ybff;
    ushort* z_silu = (ushort*)zbff;
    ushort* Wt6    = (ushort*)wt6f;

    // C0: converts (hs flat; weights transposed to [N,K] bf16)
    hipLaunchKernelGGL(convert_bf16_flat, dim3(8192), dim3(256), 0, stream,
                       hs, hs_bf, NROW * D_MODEL / 4);
    hipLaunchKernelGGL(transpose_bf16, dim3(4096 / 32, 1024 / 32), dim3(256), 0, stream,
                       in_proj_w, Wt1, 1024, 4096);
    hipLaunchKernelGGL(transpose_bf16, dim3(1024 / 32, 2048 / 32), dim3(256), 0, stream,
                       out_proj_w, Wt6, 2048, 1024);

    // K1: in_proj (bf16 MFMA NT, reg-staged+swz+prefetch) -> x fp32 + silu(z) bf16
    hipLaunchKernelGGL((gemm_bf16_nt<1>), dim3(4096 / 128, NROW / 128), dim3(256), 0, stream,
                       hs_bf, Wt1, regA, z_silu, NROW, 4096, D_MODEL, 0);

    // K2: depthwise conv + bias + silu -> x_bld (float4-vectorized)
    {
        const int total4 = B_SZ * L_SEQ * D_INNER / 4;
        hipLaunchKernelGGL(conv_silu_kernel, dim3((total4 + 255) / 256), dim3(256), 0, stream,
                           regA, conv_w, conv_b, x_bld);
    }
    // K3: x_dbl = x_bld @ x_proj_w  (split-K fp32)
    {
        hipLaunchKernelGGL(xproj_partial, dim3(NROW / 64, KSPLIT), dim3(256), 0, stream,
                           x_bld, x_proj_w, part);
        hipLaunchKernelGGL(xproj_reduce, dim3(NROW * 96 / 4 / 256), dim3(256), 0, stream,
                           part, x_dbl);
    }
    // K4: delta -> regA (x dead after conv)
    {
        dim3 grid(D_INNER / 256, NROW / 16);
        hipLaunchKernelGGL(dt_softplus_kernel, grid, dim3(256), 0, stream,
                           x_dbl, dt_proj_w, dt_proj_b, regA);
    }
    // K5: chunked scan (thread-local 16-state); pass3 emits bf16 y directly
    {
        const int total1 = B_SZ * D_INNER * NCHUNK;          // 524,288
        hipLaunchKernelGGL(scan_pass1, dim3(total1 / 256), dim3(256), 0, stream,
                           regA, x_bld, x_dbl, A_log, hfin, Ssum);
        const int total2 = B_SZ * D_INNER * D_STATE;         // 131,072
        hipLaunchKernelGGL(scan_pass2, dim3(total2 / 256), dim3(256), 0, stream,
                           hfin, Ssum, A_log);
        hipLaunchKernelGGL(scan_pass3, dim3(total1 / 256), dim3(256), 0, stream,
                           regA, x_bld, z_silu, x_dbl, A_log, D_skip, hfin, y_bf);
    }
    // K6: out = y @ out_proj_w  (bf16 MFMA NT, reg-staged+swz+prefetch)
    hipLaunchKernelGGL((gemm_bf16_nt<0>), dim3(1024 / 128, NROW / 128), dim3(256), 0, stream,
                       y_bf, Wt6, out, (ushort*)nullptr, NROW, 1024, D_INNER, 1024);
}